// Round 3
// baseline (149.636 us; speedup 1.0000x reference)
//
#include <hip/hip_runtime.h>
#include <math.h>

namespace {

constexpr int BB  = 4;    // batch
constexpr int SS  = 512;  // detector bins == image size
constexpr int AA  = 180;  // angles
constexpr int PAD = 112;  // LDS row zero-pad each side: p in [6.1, 728.9]
constexpr int ROWBUF = SS + 2 * PAD;  // 736 floats

// workspace float offsets
constexpr int XF_OFF   = 0;                    // 720*512 = 368640 floats
constexpr int XF_FLOATS = BB * AA * SS;        // 368640
constexpr int G0_OFF   = XF_FLOATS;            // 528 floats (taps, parity 0, pre-scaled)
constexpr int G1_OFF   = G0_OFF + 528;         // 528 floats (taps, parity 1)
constexpr int TRIG_OFF = G1_OFF + 528;         // 180 float2 (cos*255.5, sin*255.5)

// ---------------------------------------------------------------------------
// init: zero xf (atomic target) + build pre-scaled tap tables + trig table.
//   hh[k] = -2/(pi*(2k-511))^2  (odd-tap ramp filter), pre-scaled by pi/360.
//   G_p[i] = s*hh[i+p] for i+p in [0,512), else 0.  (per-parity base => all
//   lanes' float4 windows in the ramp kernel are 16B-aligned)
// ---------------------------------------------------------------------------
__global__ __launch_bounds__(256) void init_kernel(float* __restrict__ ws) {
  const int t = threadIdx.x;
  const int i = blockIdx.x * 256 + t;
  if (i < XF_FLOATS) ws[XF_OFF + i] = 0.0f;
  if (blockIdx.x == 0) {
    const double s = M_PI / 360.0;
    for (int k = t; k < 528; k += 256) {
      // parity 0
      {
        int kk = k;
        double d = (double)(2 * kk - 511);
        ws[G0_OFF + k] = (kk < 512) ? (float)(s * (-2.0 / (M_PI * M_PI * d * d))) : 0.0f;
      }
      // parity 1
      {
        int kk = k + 1;
        double d = (double)(2 * kk - 511);
        ws[G1_OFF + k] = (kk < 512) ? (float)(s * (-2.0 / (M_PI * M_PI * d * d))) : 0.0f;
      }
    }
    if (t < AA) {
      float th = (float)t * (float)(M_PI / 180.0);
      float sn, cn;
      sincosf(th, &sn, &cn);
      ((float2*)(ws + TRIG_OFF))[t] = make_float2(cn * 255.5f, sn * 255.5f);
    }
  }
}

// ---------------------------------------------------------------------------
// Kernel 1: ramp filter, register-tiled Toeplitz conv.
//   y[n] = s*0.5*x[n] + sum_{j=0}^{255} s*hh[8*idx+r-j+255+p] * x[m(j)]
// Thread layout: col = t>>6 (4 angle-columns/block, wave-uniform),
//   p = (t&63)>>5 (output parity), idx = t&31, outputs n = p + 16*idx + 2r.
// j split into 4 chunks of 64 across blockIdx.z (grid 720) -> atomicAdd xf.
// Taps: global L1-resident table, sliding 12-float register window,
//   1 aligned dwordx4 per 4 j (lane window base A = 8*idx+252-64c-4q, =0 mod 4).
// x values: parity-split LDS, 1 broadcast ds_read_b128 per 4 j.
// DS+VMEM per 32 FMAs: 2 instructions (was 64 scalar ds_read in R2).
// ---------------------------------------------------------------------------
__global__ __launch_bounds__(256) void ramp_filter_kernel(
    const float* __restrict__ x, float* __restrict__ ws) {
  __shared__ __align__(16) float xs[4][2][64];  // [col][m-parity][m>>1 within chunk]
  const int t  = threadIdx.x;
  const int a0 = blockIdx.x * 4;
  const int b  = blockIdx.y;
  const int c  = blockIdx.z;  // j-chunk: j in [64c, 64c+64), m in [128c, 128c+128)

  // stage 128 m-rows x 4 cols, parity-split (threads 0..127, one float4 each)
  if (t < 128) {
    const int m = 128 * c + t;
    float4 v = *(const float4*)(x + (size_t)b * (SS * AA) + (size_t)m * AA + a0);
    xs[0][t & 1][t >> 1] = v.x;
    xs[1][t & 1][t >> 1] = v.y;
    xs[2][t & 1][t >> 1] = v.z;
    xs[3][t & 1][t >> 1] = v.w;
  }
  __syncthreads();

  const int col = t >> 6;
  const int p   = (t & 63) >> 5;
  const int idx = t & 31;

  const float* Gp  = ws + (p ? G1_OFF : G0_OFF);
  const float* xsp = &xs[col][1 - p][0];

  float acc[8];
#pragma unroll
  for (int r = 0; r < 8; ++r) acc[r] = 0.0f;

  // window W[0..11] = Gp[A .. A+11], A = 8*idx + 252 - 64c - 4q
  const int A0 = 8 * idx + 252 - 64 * c;
  float W[12];
  {
    float4 w0 = *(const float4*)(Gp + A0);
    float4 w1 = *(const float4*)(Gp + A0 + 4);
    float4 w2 = *(const float4*)(Gp + A0 + 8);
    W[0] = w0.x; W[1] = w0.y; W[2] = w0.z; W[3] = w0.w;
    W[4] = w1.x; W[5] = w1.y; W[6] = w1.z; W[7] = w1.w;
    W[8] = w2.x; W[9] = w2.y; W[10] = w2.z; W[11] = w2.w;
  }

#pragma unroll
  for (int q = 0; q < 16; ++q) {
    const float4 xv4 = *(const float4*)(xsp + 4 * q);
    float4 nw;
    if (q != 15) nw = *(const float4*)(Gp + A0 - 4 * (q + 1));
    // tap for (j = 4q+d, output r) is W[3 - d + r]
#pragma unroll
    for (int r = 0; r < 8; ++r) {
      acc[r] = fmaf(W[3 + r], xv4.x, acc[r]);
      acc[r] = fmaf(W[2 + r], xv4.y, acc[r]);
      acc[r] = fmaf(W[1 + r], xv4.z, acc[r]);
      acc[r] = fmaf(W[0 + r], xv4.w, acc[r]);
    }
    if (q != 15) {
      // slide window down by 4 (compile-time rotation)
#pragma unroll
      for (int i = 11; i >= 4; --i) W[i] = W[i - 4];
      W[0] = nw.x; W[1] = nw.y; W[2] = nw.z; W[3] = nw.w;
    }
  }

  // self-term (n falls in this chunk's m-range iff idx>>3 == c)
  if ((idx >> 3) == c) {
    const float self = (float)(0.5 * M_PI / 360.0);
    const int slot = 8 * (idx & 7);
#pragma unroll
    for (int r = 0; r < 8; ++r)
      acc[r] = fmaf(self, xs[col][p][slot + r], acc[r]);
  }

  float* xf = ws + XF_OFF;
  const size_t ocol = ((size_t)b * AA + a0 + col) * SS;
#pragma unroll
  for (int r = 0; r < 8; ++r)
    unsafeAtomicAdd(&xf[ocol + p + 16 * idx + 2 * r], acc[r]);
}

// ---------------------------------------------------------------------------
// Kernel 2: backprojection, angle-split x4, global_load_lds staging.
// Grid (8, 32, 16): x-tile(64 px), y-tile(16 px), z = b*4 + angle-chunk.
// Each block: 45 angles in 15 groups of 3, double-buffered LDS rows staged
// with __builtin_amdgcn_global_load_lds width=16 (wave-uniform LDS base +
// lane*16). One barrier per group. Scale is pre-folded into xf; circle mask
// folded into the epilogue (outside lanes skip the atomic; d_out memset to 0).
// ---------------------------------------------------------------------------
__global__ __launch_bounds__(256) void backproject_kernel(
    const float* __restrict__ ws, float* __restrict__ out) {
  __shared__ __align__(16) float rows[2][3][ROWBUF];

  const int t     = threadIdx.x;
  const int w     = t >> 6;
  const int lane  = t & 63;
  const int tx    = blockIdx.x;       // 0..7
  const int ty    = blockIdx.y;       // 0..31
  const int b     = blockIdx.z >> 2;
  const int chunk = blockIdx.z & 3;
  const int a0    = chunk * 45;

  // zero pad regions once (published by the prologue barrier)
  for (int i = t; i < 2 * 3 * 2 * PAD; i += 256) {
    int rr = i / (2 * PAD);
    int o  = i - rr * (2 * PAD);
    int off = (o < PAD) ? o : (o + SS);
    rows[rr / 3][rr % 3][off] = 0.0f;
  }

  const float* xf_src = ws + XF_OFF + ((size_t)b * AA + a0) * SS;
  const float2* trig  = (const float2*)(ws + TRIG_OFF);

  // stage 3 rows (6 KB = 6 segments of 1 KB) into rows[buf] via LDS-DMA.
  // seg s: row rr = s>>1, half h = s&1. wave w stages seg w (+ seg 4+w if w<2).
  auto stage = [&](int g, int buf) {
    const float* base = xf_src + (size_t)(g * 3) * SS;
    {
      const int s = w;
      const float* gp = base + (s >> 1) * SS + (s & 1) * 256 + lane * 4;
      void* lp = (void*)&rows[buf][s >> 1][PAD + (s & 1) * 256];
      __builtin_amdgcn_global_load_lds(
          (const __attribute__((address_space(1))) void*)gp,
          (__attribute__((address_space(3))) void*)lp, 16, 0, 0);
    }
    if (w < 2) {
      const int s = 4 + w;
      const float* gp = base + (s >> 1) * SS + (s & 1) * 256 + lane * 4;
      void* lp = (void*)&rows[buf][s >> 1][PAD + (s & 1) * 256];
      __builtin_amdgcn_global_load_lds(
          (const __attribute__((address_space(1))) void*)gp,
          (__attribute__((address_space(3))) void*)lp, 16, 0, 0);
    }
  };

  const int gx = tx * 64 + lane;
  const int r4 = w;  // y sub-row 0..3
  // EXACT replication of jnp.linspace(-1,1,512) + f32 mask math (no FMA!)
  const float step = 2.0f / 511.0f;
  const float xg = __fadd_rn(-1.0f, __fmul_rn((float)gx, step));
  float yg[4], dy[4];
  int   gy[4];
#pragma unroll
  for (int kk = 0; kk < 4; ++kk) {
    gy[kk] = ty * 16 + r4 + 4 * kk;
    yg[kk] = __fadd_rn(-1.0f, __fmul_rn((float)gy[kk], step));
    dy[kk] = -yg[kk];
  }

  const float Kp = 255.5f + (float)PAD;
  float acc[4] = {0.f, 0.f, 0.f, 0.f};

  stage(0, 0);
  __syncthreads();

  int buf = 0;
  for (int g = 0; g < 15; ++g) {
    if (g + 1 < 15) stage(g + 1, buf ^ 1);
#pragma unroll
    for (int aa = 0; aa < 3; ++aa) {
      const float2 cs = trig[a0 + g * 3 + aa];
      const float base = fmaf(xg, cs.x, Kp);
      const float* R = rows[buf][aa];
#pragma unroll
      for (int kk = 0; kk < 4; ++kk) {
        float p  = fmaf(dy[kk], cs.y, base);  // > 0 always
        int   i0 = (int)p;
        float wt = p - (float)i0;
        float v0 = R[i0];
        float v1 = R[i0 + 1];                 // -> ds_read2_b32
        acc[kk] += v0 + wt * (v1 - v0);
      }
    }
    __syncthreads();
    buf ^= 1;
  }

  // epilogue: circle mask folded into predicated atomic (out pre-zeroed).
  const float xx = __fmul_rn(xg, xg);
#pragma unroll
  for (int kk = 0; kk < 4; ++kk) {
    float ss = __fadd_rn(xx, __fmul_rn(yg[kk], yg[kk]));
    if (ss <= 1.0f)
      unsafeAtomicAdd(&out[((size_t)b * SS + gy[kk]) * SS + gx], acc[kk]);
  }
}

}  // namespace

extern "C" void kernel_launch(void* const* d_in, const int* in_sizes, int n_in,
                              void* d_out, int out_size, void* d_ws, size_t ws_size,
                              hipStream_t stream) {
  const float* x   = (const float*)d_in[0];
  float*       out = (float*)d_out;
  float*       ws  = (float*)d_ws;  // ~1.48 MB used

  hipMemsetAsync(d_out, 0, (size_t)out_size * sizeof(float), stream);
  init_kernel<<<(XF_FLOATS + 255) / 256, 256, 0, stream>>>(ws);
  ramp_filter_kernel<<<dim3(45, BB, 4), 256, 0, stream>>>(x, ws);
  backproject_kernel<<<dim3(8, 32, 16), 256, 0, stream>>>(ws, out);
}

// Round 4
// 106.852 us; speedup vs baseline: 1.4004x; 1.4004x over previous
//
#include <hip/hip_runtime.h>
#include <math.h>

namespace {

constexpr int BB  = 4;    // batch
constexpr int SS  = 512;  // detector bins == image size
constexpr int AA  = 180;  // angles
constexpr int PAD = 112;  // LDS row zero-pad each side: p in [6.1, 728.9]
constexpr int ROWBUF = SS + 2 * PAD;  // 736 floats

// ---------------------------------------------------------------------------
// Kernel 1: ramp filter, register-tiled Toeplitz conv, NO atomics/init.
//   y[n] = s*0.5*x[n] + sum_j hh[k(n,j)]*x[m(j)],  hh[k] = s*(-2/pi^2)/(2k-511)^2
// Block: 2 angle-columns, full K. Threads: col=t>>7, p=(t>>6)&1, idx=t&63;
// outputs n = p + 8*idx + 2r, r in [0,4). Taps in per-parity LDS tables
// G[p][i] = hh[i+p] so lane windows (A = 4*idx+252-4q) are 16B-aligned.
// Per q (4 j-steps): 1 broadcast ds_read_b128 (x) + 1 ds_read_b128 (taps,
// lane-consecutive) + 16 FMA. tap slot = 3 + r - d, d = j&3.
// ---------------------------------------------------------------------------
__global__ __launch_bounds__(256) void ramp_filter_kernel(
    const float* __restrict__ x, float* __restrict__ xf) {
  __shared__ __align__(16) float xs[2][2][256];  // [col][m-parity][m>>1]
  __shared__ __align__(16) float G[2][528];      // per-parity scaled taps
  const int t  = threadIdx.x;
  const int a0 = blockIdx.x * 2;
  const int b  = blockIdx.y;

  // build scaled tap tables (f32; taps ~1e-7 rel err, irrelevant at 4.4e-3 thr)
  const float s  = (float)(M_PI / 360.0);
  const float cc = (float)(-2.0 / (M_PI * M_PI)) * s;
  for (int i = t; i < 528; i += 256) {
    { int kk = i;     float d = (float)(2 * kk - 511); G[0][i] = (kk < 512) ? cc / (d * d) : 0.0f; }
    { int kk = i + 1; float d = (float)(2 * kk - 511); G[1][i] = (kk < 512) ? cc / (d * d) : 0.0f; }
  }

  // stage both columns, parity-split (two float2 per thread, stride 720 B)
  const float* xb = x + (size_t)b * (SS * AA) + a0;
  {
    int m = t;
    float2 v = *(const float2*)(xb + (size_t)m * AA);
    xs[0][m & 1][m >> 1] = v.x;  xs[1][m & 1][m >> 1] = v.y;
    m = t + 256;
    float2 v2 = *(const float2*)(xb + (size_t)m * AA);
    xs[0][m & 1][m >> 1] = v2.x; xs[1][m & 1][m >> 1] = v2.y;
  }
  __syncthreads();

  const int col = t >> 7;
  const int p   = (t >> 6) & 1;
  const int idx = t & 63;
  const float* Gp = G[p];
  const float* xv = xs[col][1 - p];

  float acc[4] = {0.f, 0.f, 0.f, 0.f};
  float W[8];  // W[s] = G[p][A + s], A = 4*idx + 252 - 4q; slot(r,d) = 3+r-d
  {
    const int A0 = 4 * idx + 252;
    float4 w0 = *(const float4*)(Gp + A0);
    float4 w1 = *(const float4*)(Gp + A0 + 4);
    W[0] = w0.x; W[1] = w0.y; W[2] = w0.z; W[3] = w0.w;
    W[4] = w1.x; W[5] = w1.y; W[6] = w1.z; W[7] = w1.w;
  }

#pragma unroll
  for (int q = 0; q < 64; ++q) {
    const float4 xq = *(const float4*)(xv + 4 * q);  // broadcast
    float4 nw;
    if (q != 63) nw = *(const float4*)(Gp + (4 * idx + 252 - 4 * (q + 1)));
#pragma unroll
    for (int r = 0; r < 4; ++r) {
      acc[r] = fmaf(W[3 + r], xq.x, acc[r]);
      acc[r] = fmaf(W[2 + r], xq.y, acc[r]);
      acc[r] = fmaf(W[1 + r], xq.z, acc[r]);
      acc[r] = fmaf(W[0 + r], xq.w, acc[r]);
    }
    if (q != 63) {
      W[7] = W[3]; W[6] = W[2]; W[5] = W[1]; W[4] = W[0];
      W[0] = nw.x; W[1] = nw.y; W[2] = nw.z; W[3] = nw.w;
    }
  }

  // self term: x[n] lives at xs[col][p][4*idx + r]
  const float selfc = 0.5f * s;
  const float* xsp = xs[col][p];
  float* orow = xf + ((size_t)(b * AA + a0 + col)) * SS;
#pragma unroll
  for (int r = 0; r < 4; ++r) {
    orow[p + 8 * idx + 2 * r] = fmaf(selfc, xsp[4 * idx + r], acc[r]);
  }
}

// ---------------------------------------------------------------------------
// Kernel 2: backprojection, 8 px/thread, angle-split x4, DMA staging.
// Grid (8, 16, 16): x-tile(64 px), y-tile(32 px), z = b*4 + chunk(45 angles).
// 2048 blocks = 8/CU (32 waves/CU, LDS 18 KB). 15 groups of 3 angles,
// double-buffered global_load_lds width=16. Per sample: 7 VALU + 1 ds_read2.
// Scale pre-folded into taps; circle mask = predicated atomic (out zeroed).
// ---------------------------------------------------------------------------
__global__ __launch_bounds__(256) void backproject_kernel(
    const float* __restrict__ xf, float* __restrict__ out) {
  __shared__ __align__(16) float rows[2][3][ROWBUF];
  __shared__ float2 trig_s[45];

  const int t     = threadIdx.x;
  const int w     = t >> 6;
  const int lane  = t & 63;
  const int tx    = blockIdx.x;       // 0..7
  const int ty    = blockIdx.y;       // 0..15
  const int b     = blockIdx.z >> 2;
  const int chunk = blockIdx.z & 3;
  const int a0    = chunk * 45;

  // zero pad regions once
  for (int i = t; i < 2 * 3 * 2 * PAD; i += 256) {
    int rr = i / (2 * PAD);
    int o  = i - rr * (2 * PAD);
    int off = (o < PAD) ? o : (o + SS);
    rows[rr / 3][rr % 3][off] = 0.0f;
  }
  // per-block trig (same sincosf values as before -> same numerics)
  if (t < 45) {
    float th = (float)(a0 + t) * (float)(M_PI / 180.0);
    float sn, cn;
    sincosf(th, &sn, &cn);
    trig_s[t] = make_float2(cn * 255.5f, sn * 255.5f);
  }

  const float* xf_src = xf + ((size_t)b * AA + a0) * SS;

  auto stage = [&](int g, int buf) {
    const float* base = xf_src + (size_t)(g * 3) * SS;
    {
      const int s = w;
      const float* gp = base + (s >> 1) * SS + (s & 1) * 256 + lane * 4;
      void* lp = (void*)&rows[buf][s >> 1][PAD + (s & 1) * 256];
      __builtin_amdgcn_global_load_lds(
          (const __attribute__((address_space(1))) void*)gp,
          (__attribute__((address_space(3))) void*)lp, 16, 0, 0);
    }
    if (w < 2) {
      const int s = 4 + w;
      const float* gp = base + (s >> 1) * SS + (s & 1) * 256 + lane * 4;
      void* lp = (void*)&rows[buf][s >> 1][PAD + (s & 1) * 256];
      __builtin_amdgcn_global_load_lds(
          (const __attribute__((address_space(1))) void*)gp,
          (__attribute__((address_space(3))) void*)lp, 16, 0, 0);
    }
  };

  const int gx = tx * 64 + lane;
  // EXACT replication of jnp.linspace(-1,1,512) + f32 mask math (no FMA!)
  const float step = 2.0f / 511.0f;
  const float xg = __fadd_rn(-1.0f, __fmul_rn((float)gx, step));
  float dy[8];  // dy = -yg (negation exact; dy*dy == yg*yg bitwise)
#pragma unroll
  for (int kk = 0; kk < 8; ++kk) {
    int gy = ty * 32 + w + 4 * kk;
    dy[kk] = -__fadd_rn(-1.0f, __fmul_rn((float)gy, step));
  }

  const float Kp = 255.5f + (float)PAD;
  float acc[8] = {0.f, 0.f, 0.f, 0.f, 0.f, 0.f, 0.f, 0.f};

  stage(0, 0);
  __syncthreads();

  int buf = 0;
  for (int g = 0; g < 15; ++g) {
    if (g + 1 < 15) stage(g + 1, buf ^ 1);
#pragma unroll
    for (int aa = 0; aa < 3; ++aa) {
      const float2 cs = trig_s[g * 3 + aa];
      const float base = fmaf(xg, cs.x, Kp);
      const float* R = rows[buf][aa];
#pragma unroll
      for (int kk = 0; kk < 8; ++kk) {
        float p  = fmaf(dy[kk], cs.y, base);  // > 0 always
        int   i0 = (int)p;                    // trunc == floor (p > 0)
#if __has_builtin(__builtin_amdgcn_fractf)
        float wt = __builtin_amdgcn_fractf(p);
#else
        float wt = p - floorf(p);
#endif
        float v0 = R[i0];
        float v1 = R[i0 + 1];                 // -> ds_read2_b32
        acc[kk] = fmaf(wt, v1 - v0, acc[kk] + v0);
      }
    }
    __syncthreads();
    buf ^= 1;
  }

  // epilogue: circle mask folded into predicated atomic (out pre-zeroed)
  const float xx = __fmul_rn(xg, xg);
#pragma unroll
  for (int kk = 0; kk < 8; ++kk) {
    float ss = __fadd_rn(xx, __fmul_rn(dy[kk], dy[kk]));
    if (ss <= 1.0f) {
      int gy = ty * 32 + w + 4 * kk;
      unsafeAtomicAdd(&out[((size_t)b * SS + gy) * SS + gx], acc[kk]);
    }
  }
}

}  // namespace

extern "C" void kernel_launch(void* const* d_in, const int* in_sizes, int n_in,
                              void* d_out, int out_size, void* d_ws, size_t ws_size,
                              hipStream_t stream) {
  const float* x   = (const float*)d_in[0];
  float*       out = (float*)d_out;
  float*       xf  = (float*)d_ws;  // [B][A][S] = 1.44 MB, direct-stored

  hipMemsetAsync(d_out, 0, (size_t)out_size * sizeof(float), stream);
  ramp_filter_kernel<<<dim3(AA / 2, BB), 256, 0, stream>>>(x, xf);
  backproject_kernel<<<dim3(8, 16, 16), 256, 0, stream>>>(xf, out);
}